// Round 3
// baseline (3911.654 us; speedup 1.0000x reference)
//
#include <hip/hip_runtime.h>
#include <hip/hip_bf16.h>

// ---------------------------------------------------------------------------
// RecurrentAutoencoder on MI355X (gfx950).
// Stage A: LSTM e1  (B=4096, T=140, in=1,  hid=128)  -> h1[4096][128]
// Stage B: Up = permuted input-projection (parallel), serial scan T=4096 -> z
// Stage C+D: decoder LSTMs fused, T=140, single workgroup -> out[140]
//
// Round-3 change: ALL cross-lane reduces/rotates moved from ds_swizzle
// (DS pipe, ~120 cyc latency) to DPP (VALU pipe, ~4 cyc).
// ---------------------------------------------------------------------------

__device__ __forceinline__ float sigm(float x) {
  return 1.0f / (1.0f + __expf(-x));
}
__device__ __forceinline__ float tanh_fast(float x) {
  return 1.0f - 2.0f / (__expf(2.0f * x) + 1.0f);
}

// DPP move: returns src value moved per CTRL (row-of-16 scope), VALU pipe.
template <int CTRL>
__device__ __forceinline__ float dppmv(float v) {
  return __int_as_float(__builtin_amdgcn_update_dpp(
      0, __float_as_int(v), CTRL, 0xF, 0xF, true));
}
#define DPP_XOR1   0xB1   // quad_perm [1,0,3,2]
#define DPP_XOR2   0x4E   // quad_perm [2,3,0,1]
#define DPP_ROT1   0x93   // quad_perm [3,0,1,2]: dest q <- (q-1)&3
#define DPP_HMIRR  0x141  // row_half_mirror (lane ^ 7 within 8)
#define DPP_MIRR   0x140  // row_mirror      (lane ^ 15 within 16)

// swizzled LDS column for 128-wide rows: quarter q shifted by 4 floats
__device__ __forceinline__ int swzc(int k) { return k + ((k >> 5) << 2); }

#define A_BB 16

// ---------------------------------------------------------------------------
// Stage A. 512 threads = 8 waves. Thread: u = wave*16 + (lane>>2) in [0,128),
// q = lane&3. Owns gate rows {u,128+u,256+u,384+u}, k in [32q,32q+32), and the
// c-state of unit u for batches [4q,4q+4). 4-stage ring reduce-scatter (DPP
// rotate) puts complete gate sums for those batches in static registers.
// ---------------------------------------------------------------------------
__global__ __launch_bounds__(512, 2) void lstm_e1_kernel(
    const float* __restrict__ x,     // [4096][140]
    const float* __restrict__ Wih,   // [512][1]
    const float* __restrict__ Whh,   // [512][128]
    const float* __restrict__ bih,   // [512]
    const float* __restrict__ bhh,   // [512]
    float* __restrict__ h1_out)      // [4096][128]
{
  const int j    = threadIdx.x;
  const int lane = j & 63;
  const int w    = j >> 6;
  const int u    = w * 16 + (lane >> 2);  // 0..127
  const int q    = lane & 3;
  const int b0   = blockIdx.x * A_BB;

  __shared__ float Hs[2][A_BB][144];  // swizzled columns
  __shared__ float xs[2][A_BB];

  for (int i = j; i < A_BB * 144; i += 512) ((float*)Hs[0])[i] = 0.0f;
  if (j < A_BB) xs[0][j] = x[(b0 + j) * 140];

  float wr[4][32];
#pragma unroll
  for (int g = 0; g < 4; ++g)
#pragma unroll
    for (int k = 0; k < 32; k += 4)
      *(float4*)&wr[g][k] = *(const float4*)&Whh[(g * 128 + u) * 128 + q * 32 + k];

  float wih[4], bs[4];
#pragma unroll
  for (int g = 0; g < 4; ++g) {
    wih[g] = Wih[g * 128 + u];
    bs[g]  = bih[g * 128 + u] + bhh[g * 128 + u];
  }

  float c[4]  = {0.f, 0.f, 0.f, 0.f};
  float hr[4] = {0.f, 0.f, 0.f, 0.f};
  __syncthreads();

  int cur = 0;
  for (int t = 0; t < 140; ++t) {
    const int nxt = cur ^ 1;

    float R[4][4];
#pragma unroll
    for (int g = 0; g < 4; ++g)
#pragma unroll
      for (int i = 0; i < 4; ++i) R[g][i] = 0.0f;

#pragma unroll
    for (int s = 0; s < 4; ++s) {
      if (s) {
#pragma unroll
        for (int g = 0; g < 4; ++g)
#pragma unroll
          for (int i = 0; i < 4; ++i) R[g][i] = dppmv<DPP_ROT1>(R[g][i]);
      }
      const int cch = (q - 1 - s) & 3;  // batch chunk visited this stage
      const float* hbase = &Hs[cur][cch * 4][q * 36];
#pragma unroll
      for (int i = 0; i < 4; ++i) {
        const float* hrow = hbase + i * 144;
#pragma unroll
        for (int kk = 0; kk < 8; ++kk) {
          const float4 hv = *(const float4*)&hrow[kk * 4];
#pragma unroll
          for (int g = 0; g < 4; ++g) {
            R[g][i] = __builtin_fmaf(wr[g][kk * 4 + 0], hv.x, R[g][i]);
            R[g][i] = __builtin_fmaf(wr[g][kk * 4 + 1], hv.y, R[g][i]);
            R[g][i] = __builtin_fmaf(wr[g][kk * 4 + 2], hv.z, R[g][i]);
            R[g][i] = __builtin_fmaf(wr[g][kk * 4 + 3], hv.w, R[g][i]);
          }
        }
      }
    }

    if (j < A_BB && (t + 1) < 140) xs[nxt][j] = x[(b0 + j) * 140 + t + 1];

    const float4 xv = *(const float4*)&xs[cur][q * 4];
    const float xa[4] = {xv.x, xv.y, xv.z, xv.w};
#pragma unroll
    for (int i = 0; i < 4; ++i) {
      const float gi = sigm(R[0][i] + __builtin_fmaf(wih[0], xa[i], bs[0]));
      const float gf = sigm(R[1][i] + __builtin_fmaf(wih[1], xa[i], bs[1]));
      const float gg = tanh_fast(R[2][i] + __builtin_fmaf(wih[2], xa[i], bs[2]));
      const float go = sigm(R[3][i] + __builtin_fmaf(wih[3], xa[i], bs[3]));
      c[i]  = gf * c[i] + gi * gg;
      hr[i] = go * tanh_fast(c[i]);
      Hs[nxt][q * 4 + i][swzc(u)] = hr[i];
    }
    __syncthreads();
    cur = nxt;
  }

#pragma unroll
  for (int i = 0; i < 4; ++i)
    h1_out[(b0 + q * 4 + i) * 128 + u] = hr[i];
}

// ---------------------------------------------------------------------------
// Stage B input projection, PERMUTED output:
// Up[t][u] = float4( pre_i, pre_f, pre_g, pre_o ) for unit u (biases folded).
// ---------------------------------------------------------------------------
__global__ __launch_bounds__(256, 1) void u_pre_kernel(
    const float* __restrict__ h1,   // [4096][128]
    const float* __restrict__ Wih,  // [256][128]
    const float* __restrict__ bih,  // [256]
    const float* __restrict__ bhh,  // [256]
    float* __restrict__ Up)         // [4096][64][4]
{
  const int t = blockIdx.x;
  const int j = threadIdx.x;      // gate row j = g*64 + u
  __shared__ float hs[128];
  if (j < 128) hs[j] = h1[t * 128 + j];
  __syncthreads();
  float acc = bih[j] + bhh[j];
#pragma unroll
  for (int k = 0; k < 128; k += 4) {
    const float4 hv = *(const float4*)&hs[k];
    const float4 wv = *(const float4*)&Wih[j * 128 + k];
    acc += wv.x * hv.x + wv.y * hv.y + wv.z * hv.z + wv.w * hv.w;
  }
  Up[t * 256 + (j & 63) * 4 + (j >> 6)] = acc;
}

// ---------------------------------------------------------------------------
// Stage B serial scan. 512 threads = 8 waves. Thread (u = j>>3, o = j&7) owns
// gate rows {u,64+u,128+u,192+u}, k in [8o,8o+8). 8-lane DPP butterfly
// (xor1, xor2, half_mirror); c,h replicated; ONE barrier per step.
// ---------------------------------------------------------------------------
__global__ __launch_bounds__(512, 1) void lstm_e2_scan_kernel(
    const float4* __restrict__ Up,  // [4096][64] of (i,f,g,o)
    const float* __restrict__ Whh,  // [256][64]
    float* __restrict__ z_out)      // [64]
{
  const int j = threadIdx.x;
  const int u = j >> 3;   // 0..63
  const int o = j & 7;    // k-octant

  __shared__ float hb[2][64];

  float wr[4][8];
#pragma unroll
  for (int g = 0; g < 4; ++g) {
    *(float4*)&wr[g][0] = *(const float4*)&Whh[(g * 64 + u) * 64 + o * 8];
    *(float4*)&wr[g][4] = *(const float4*)&Whh[(g * 64 + u) * 64 + o * 8 + 4];
  }

  if (j < 64) hb[0][j] = 0.0f;
  float c = 0.0f, h = 0.0f;

  float4 U0 = Up[u];        // t = 0
  float4 U1 = Up[64 + u];   // t = 1
  __syncthreads();

  int cur = 0;
#pragma unroll 1
  for (int t = 0; t < 4096; t += 2) {
#pragma unroll
    for (int half = 0; half < 2; ++half) {
      const int tp = (t + 2 + half < 4096) ? (t + 2 + half) : 4095;
      const float4 Unew = Up[tp * 64 + u];
      const float4 Ucur = half ? U1 : U0;

      const float4 hv0 = *(const float4*)&hb[cur][o * 8];
      const float4 hv1 = *(const float4*)&hb[cur][o * 8 + 4];
      float a0, a1, a2, a3;
      a0 = wr[0][0] * hv0.x; a1 = wr[1][0] * hv0.x; a2 = wr[2][0] * hv0.x; a3 = wr[3][0] * hv0.x;
      a0 = __builtin_fmaf(wr[0][1], hv0.y, a0); a1 = __builtin_fmaf(wr[1][1], hv0.y, a1);
      a2 = __builtin_fmaf(wr[2][1], hv0.y, a2); a3 = __builtin_fmaf(wr[3][1], hv0.y, a3);
      a0 = __builtin_fmaf(wr[0][2], hv0.z, a0); a1 = __builtin_fmaf(wr[1][2], hv0.z, a1);
      a2 = __builtin_fmaf(wr[2][2], hv0.z, a2); a3 = __builtin_fmaf(wr[3][2], hv0.z, a3);
      a0 = __builtin_fmaf(wr[0][3], hv0.w, a0); a1 = __builtin_fmaf(wr[1][3], hv0.w, a1);
      a2 = __builtin_fmaf(wr[2][3], hv0.w, a2); a3 = __builtin_fmaf(wr[3][3], hv0.w, a3);
      a0 = __builtin_fmaf(wr[0][4], hv1.x, a0); a1 = __builtin_fmaf(wr[1][4], hv1.x, a1);
      a2 = __builtin_fmaf(wr[2][4], hv1.x, a2); a3 = __builtin_fmaf(wr[3][4], hv1.x, a3);
      a0 = __builtin_fmaf(wr[0][5], hv1.y, a0); a1 = __builtin_fmaf(wr[1][5], hv1.y, a1);
      a2 = __builtin_fmaf(wr[2][5], hv1.y, a2); a3 = __builtin_fmaf(wr[3][5], hv1.y, a3);
      a0 = __builtin_fmaf(wr[0][6], hv1.z, a0); a1 = __builtin_fmaf(wr[1][6], hv1.z, a1);
      a2 = __builtin_fmaf(wr[2][6], hv1.z, a2); a3 = __builtin_fmaf(wr[3][6], hv1.z, a3);
      a0 = __builtin_fmaf(wr[0][7], hv1.w, a0); a1 = __builtin_fmaf(wr[1][7], hv1.w, a1);
      a2 = __builtin_fmaf(wr[2][7], hv1.w, a2); a3 = __builtin_fmaf(wr[3][7], hv1.w, a3);

      // 8-lane butterfly, pure VALU
      a0 += dppmv<DPP_XOR1>(a0);  a1 += dppmv<DPP_XOR1>(a1);
      a2 += dppmv<DPP_XOR1>(a2);  a3 += dppmv<DPP_XOR1>(a3);
      a0 += dppmv<DPP_XOR2>(a0);  a1 += dppmv<DPP_XOR2>(a1);
      a2 += dppmv<DPP_XOR2>(a2);  a3 += dppmv<DPP_XOR2>(a3);
      a0 += dppmv<DPP_HMIRR>(a0); a1 += dppmv<DPP_HMIRR>(a1);
      a2 += dppmv<DPP_HMIRR>(a2); a3 += dppmv<DPP_HMIRR>(a3);

      const float gi = sigm(a0 + Ucur.x);
      const float gf = sigm(a1 + Ucur.y);
      const float gg = tanh_fast(a2 + Ucur.z);
      const float go = sigm(a3 + Ucur.w);
      c = gf * c + gi * gg;
      h = go * tanh_fast(c);
      if (o == 0) hb[cur ^ 1][u] = h;
      if (half) U1 = Unew; else U0 = Unew;
      __syncthreads();
      cur ^= 1;
    }
  }
  if (o == 0) z_out[u] = h;
}

// ---------------------------------------------------------------------------
// Stage C+D fused decoder. 512 threads; thread (u = j>>2, q = j&3) runs d1
// with DPP quad reduce; wave 0 then runs d2 row-per-gate (DPP butterfly +
// wave-synchronous LDS broadcast, no extra barrier).
// ---------------------------------------------------------------------------
__global__ __launch_bounds__(512, 1) void lstm_dec_kernel(
    const float* __restrict__ z,      // [64]
    const float* __restrict__ Wih1,   // [512][64]
    const float* __restrict__ Whh1,   // [512][128]
    const float* __restrict__ bih1,   // [512]
    const float* __restrict__ bhh1,   // [512]
    const float* __restrict__ Wih2,   // [4][128]
    const float* __restrict__ Whh2,   // [4][1]
    const float* __restrict__ bih2,   // [4]
    const float* __restrict__ bhh2,   // [4]
    float* __restrict__ out)          // [140]
{
  const int j = threadIdx.x;
  const int u = j >> 2;   // 0..127
  const int q = j & 3;

  __shared__ float hb[2][144];  // swizzled columns
  __shared__ float zs[64];
  __shared__ float act4[4];     // d2 gate sums (wave-0 private)

  if (j < 64) zs[j] = z[j];
  if (j < 144) hb[0][j] = 0.0f;
  __syncthreads();

  float wr[4][32];
#pragma unroll
  for (int g = 0; g < 4; ++g)
#pragma unroll
    for (int k = 0; k < 32; k += 4)
      *(float4*)&wr[g][k] = *(const float4*)&Whh1[(g * 128 + u) * 128 + q * 32 + k];

  float pre0[4];
#pragma unroll
  for (int g = 0; g < 4; ++g) {
    float acc = bih1[g * 128 + u] + bhh1[g * 128 + u];
#pragma unroll
    for (int k = 0; k < 64; k += 4) {
      const float4 zv = *(const float4*)&zs[k];
      const float4 wv = *(const float4*)&Wih1[(g * 128 + u) * 64 + k];
      acc += wv.x * zv.x + wv.y * zv.y + wv.z * zv.z + wv.w * zv.w;
    }
    pre0[g] = acc;
  }

  // d2 lane data: wave 0, lane l: gate g2 = l>>4, elems [8*(l&15), +8)
  const int g2  = j >> 4;
  const int i16 = j & 15;
  float w2d[8] = {0,0,0,0,0,0,0,0};
  float b2 = 0.0f, wh2 = 0.0f;
  if (j < 64) {
#pragma unroll
    for (int e = 0; e < 8; ++e) w2d[e] = Wih2[g2 * 128 + i16 * 8 + e];
    b2  = bih2[g2] + bhh2[g2];
    wh2 = Whh2[g2];
  }

  float c1 = 0.0f;
  float c2 = 0.0f, h2 = 0.0f;

  int cur = 0;
  for (int t = 0; t < 140; ++t) {
    float a0 = 0.f, a1 = 0.f, a2 = 0.f, a3 = 0.f;
#pragma unroll
    for (int kk = 0; kk < 8; ++kk) {
      const float4 hv = *(const float4*)&hb[cur][q * 36 + kk * 4];
      a0 = __builtin_fmaf(wr[0][kk*4+0], hv.x, a0); a0 = __builtin_fmaf(wr[0][kk*4+1], hv.y, a0);
      a0 = __builtin_fmaf(wr[0][kk*4+2], hv.z, a0); a0 = __builtin_fmaf(wr[0][kk*4+3], hv.w, a0);
      a1 = __builtin_fmaf(wr[1][kk*4+0], hv.x, a1); a1 = __builtin_fmaf(wr[1][kk*4+1], hv.y, a1);
      a1 = __builtin_fmaf(wr[1][kk*4+2], hv.z, a1); a1 = __builtin_fmaf(wr[1][kk*4+3], hv.w, a1);
      a2 = __builtin_fmaf(wr[2][kk*4+0], hv.x, a2); a2 = __builtin_fmaf(wr[2][kk*4+1], hv.y, a2);
      a2 = __builtin_fmaf(wr[2][kk*4+2], hv.z, a2); a2 = __builtin_fmaf(wr[2][kk*4+3], hv.w, a2);
      a3 = __builtin_fmaf(wr[3][kk*4+0], hv.x, a3); a3 = __builtin_fmaf(wr[3][kk*4+1], hv.y, a3);
      a3 = __builtin_fmaf(wr[3][kk*4+2], hv.z, a3); a3 = __builtin_fmaf(wr[3][kk*4+3], hv.w, a3);
    }
    a0 += dppmv<DPP_XOR1>(a0); a0 += dppmv<DPP_XOR2>(a0);
    a1 += dppmv<DPP_XOR1>(a1); a1 += dppmv<DPP_XOR2>(a1);
    a2 += dppmv<DPP_XOR1>(a2); a2 += dppmv<DPP_XOR2>(a2);
    a3 += dppmv<DPP_XOR1>(a3); a3 += dppmv<DPP_XOR2>(a3);

    const float gi = sigm(a0 + pre0[0]);
    const float gf = sigm(a1 + pre0[1]);
    const float gg = tanh_fast(a2 + pre0[2]);
    const float go = sigm(a3 + pre0[3]);
    c1 = gf * c1 + gi * gg;
    const float h1v = go * tanh_fast(c1);
    if (q == 0) hb[cur ^ 1][swzc(u)] = h1v;
    __syncthreads();
    cur ^= 1;

    // ---- d2 on wave 0 (wave-synchronous; no extra barrier) -----------------
    if (j < 64) {
      const int kb = i16 * 8;
      const float4 hA = *(const float4*)&hb[cur][swzc(kb)];
      const float4 hB = *(const float4*)&hb[cur][swzc(kb) + 4];
      float p = hA.x * w2d[0];
      p = __builtin_fmaf(hA.y, w2d[1], p);
      p = __builtin_fmaf(hA.z, w2d[2], p);
      p = __builtin_fmaf(hA.w, w2d[3], p);
      p = __builtin_fmaf(hB.x, w2d[4], p);
      p = __builtin_fmaf(hB.y, w2d[5], p);
      p = __builtin_fmaf(hB.z, w2d[6], p);
      p = __builtin_fmaf(hB.w, w2d[7], p);
      p += dppmv<DPP_XOR1>(p);
      p += dppmv<DPP_XOR2>(p);
      p += dppmv<DPP_HMIRR>(p);
      p += dppmv<DPP_MIRR>(p);      // full row-16 sum in every lane
      if (i16 == 0) act4[g2] = p;
      // same-wave LDS write->read: hardware lgkmcnt ordering, no barrier
      const float4 acts = *(const float4*)&act4[0];
      const float d2i = sigm(acts.x + b2 * 0.0f + (bih2[0] + bhh2[0]) * 0.0f + (acts.x * 0.0f) + (bih2[0]*0.0f) + ( (bih2[0]+bhh2[0]) ) + wh2 * 0.0f + Whh2[0] * h2);
      // NOTE: the line above must use per-gate biases; rewritten cleanly below
      (void)d2i;
      const float gi2 = sigm(acts.x + (bih2[0] + bhh2[0]) + Whh2[0] * h2);
      const float gf2 = sigm(acts.y + (bih2[1] + bhh2[1]) + Whh2[1] * h2);
      const float gg2 = tanh_fast(acts.z + (bih2[2] + bhh2[2]) + Whh2[2] * h2);
      const float go2 = sigm(acts.w + (bih2[3] + bhh2[3]) + Whh2[3] * h2);
      c2 = gf2 * c2 + gi2 * gg2;
      h2 = go2 * tanh_fast(c2);
      if (j == 0) out[t] = h2;
    }
  }
}

// ---------------------------------------------------------------------------
extern "C" void kernel_launch(void* const* d_in, const int* in_sizes, int n_in,
                              void* d_out, int out_size, void* d_ws, size_t ws_size,
                              hipStream_t stream) {
  const float* x      = (const float*)d_in[0];
  const float* Wih_e1 = (const float*)d_in[1];
  const float* Whh_e1 = (const float*)d_in[2];
  const float* bih_e1 = (const float*)d_in[3];
  const float* bhh_e1 = (const float*)d_in[4];
  const float* Wih_e2 = (const float*)d_in[5];
  const float* Whh_e2 = (const float*)d_in[6];
  const float* bih_e2 = (const float*)d_in[7];
  const float* bhh_e2 = (const float*)d_in[8];
  const float* Wih_d1 = (const float*)d_in[9];
  const float* Whh_d1 = (const float*)d_in[10];
  const float* bih_d1 = (const float*)d_in[11];
  const float* bhh_d1 = (const float*)d_in[12];
  const float* Wih_d2 = (const float*)d_in[13];
  const float* Whh_d2 = (const float*)d_in[14];
  const float* bih_d2 = (const float*)d_in[15];
  const float* bhh_d2 = (const float*)d_in[16];

  float* out = (float*)d_out;  // 140 floats

  float* h1 = (float*)d_ws;              // 4096*128
  float* Up = h1 + 4096 * 128;           // 4096*256 (permuted: [t][u][gate])
  float* zb = Up + 4096 * 256;           // 64

  lstm_e1_kernel<<<4096 / A_BB, 512, 0, stream>>>(x, Wih_e1, Whh_e1, bih_e1, bhh_e1, h1);
  u_pre_kernel<<<4096, 256, 0, stream>>>(h1, Wih_e2, bih_e2, bhh_e2, Up);
  lstm_e2_scan_kernel<<<1, 512, 0, stream>>>((const float4*)Up, Whh_e2, zb);
  lstm_dec_kernel<<<1, 512, 0, stream>>>(zb, Wih_d1, Whh_d1, bih_d1, bhh_d1,
                                         Wih_d2, Whh_d2, bih_d2, bhh_d2, out);
}